// Round 1
// baseline (20154.941 us; speedup 1.0000x reference)
//
#include <hip/hip_runtime.h>

#define KK 64
#define DD 64
#define ALPHA 0.2f
#define NEG_INF -9e15f
#define EPS 1e-8f

__global__ __launch_bounds__(256) void kgat_fused(
    const float* __restrict__ src,
    const float* __restrict__ dst,
    const float* __restrict__ rel,
    const float* __restrict__ fcw,   // [64][128] row-major: W1 = cols 0..63, W2 = cols 64..127
    const float* __restrict__ fcb,   // [64]
    const int*   __restrict__ mask,  // [N][64]
    float* __restrict__ out,
    int out_rows)
{
    __shared__ __align__(16) float s_dst[KK * DD];    // row-major [k][d]
    __shared__ __align__(16) float s_rel[KK * DD];    // row-major [k][d]
    __shared__ __align__(16) float s_w1t[DD * 65];    // W1^T padded: [f][d] at f*65+d
    __shared__ __align__(16) float s_x[DD];
    __shared__ __align__(16) float s_att[KK];
    __shared__ float s_rn[KK];
    __shared__ float s_e[KK];
    __shared__ int   s_mask[KK];

    const int tid  = threadIdx.x;
    const int lane = tid & 63;
    const int wv   = tid >> 6;
    const int n    = blockIdx.x;
    const int d    = lane;

    const float* dstp = dst + (size_t)n * (KK * DD);
    const float* relp = rel + (size_t)n * (KK * DD);

    // ---- stage dst, rel rows (coalesced float4) ----
    {
        const float4* g_d = (const float4*)dstp;
        const float4* g_r = (const float4*)relp;
        float4* l_d = (float4*)s_dst;
        float4* l_r = (float4*)s_rel;
        #pragma unroll
        for (int p = 0; p < 4; ++p) {
            int i = tid + p * 256;
            l_d[i] = g_d[i];
            l_r[i] = g_r[i];
        }
    }
    // ---- stage W1 transposed (padded 65 -> conflict-free read & write) ----
    #pragma unroll
    for (int p = 0; p < 16; ++p) {
        int idx = tid + p * 256;
        int dd = idx >> 6, ff = idx & 63;
        s_w1t[ff * 65 + dd] = fcw[dd * 128 + ff];
    }
    if (tid < 64) {
        s_x[tid]    = src[(size_t)n * DD + tid];
        s_mask[tid] = mask[(size_t)n * KK + tid];
    }

    // ---- per-lane W2 row in registers: w2col[f] = fcw[d][64+f] ----
    float w2col[64];
    {
        const float4* w4 = (const float4*)(fcw + d * 128 + 64);
        #pragma unroll
        for (int i = 0; i < 16; ++i) {
            float4 v = w4[i];
            w2col[4*i+0] = v.x; w2col[4*i+1] = v.y;
            w2col[4*i+2] = v.z; w2col[4*i+3] = v.w;
        }
    }
    float x_d = src[(size_t)n * DD + d];
    float b_d = fcb[d];

    __syncthreads();

    // ---- dW[k][d] = dot(dst[k], W2[d]) for this wave's 16 k values ----
    float acc[16];
    #pragma unroll
    for (int j = 0; j < 16; ++j) {
        const int k = wv * 16 + j;
        const float* dr = &s_dst[k * 64];
        float a = 0.f;
        #pragma unroll
        for (int f4 = 0; f4 < 16; ++f4) {
            float4 v = *(const float4*)(dr + 4 * f4);   // LDS broadcast b128
            a += v.x * w2col[4*f4+0] + v.y * w2col[4*f4+1]
               + v.z * w2col[4*f4+2] + v.w * w2col[4*f4+3];
        }
        acc[j] = a;
    }

    // ---- rel norms (layer-invariant): s_rn[k] = max(||rel_k||, eps) ----
    #pragma unroll
    for (int j = 0; j < 16; ++j) {
        const int k = wv * 16 + j;
        float r = s_rel[k * 64 + d];
        float rr = r * r;
        #pragma unroll
        for (int m = 1; m < 64; m <<= 1) rr += __shfl_xor(rr, m, 64);
        if (lane == 0) s_rn[k] = fmaxf(sqrtf(rr), EPS);
    }
    // s_rn written/read by same lane (lane 0 of own wave): no barrier needed.

    for (int ll = 0; ll < 2; ++ll) {
        // ---- s[d] = b[d] + dot(x, W1[d]) ----
        float sd = b_d;
        #pragma unroll
        for (int f4 = 0; f4 < 16; ++f4) {
            float4 xv = *(const float4*)&s_x[4 * f4];   // broadcast
            sd += xv.x * s_w1t[(4*f4+0) * 65 + d] + xv.y * s_w1t[(4*f4+1) * 65 + d]
                + xv.z * s_w1t[(4*f4+2) * 65 + d] + xv.w * s_w1t[(4*f4+3) * 65 + d];
        }

        // ---- e[k] = leaky_relu(cos(h_k, rel_k)), masked ----
        #pragma unroll
        for (int j = 0; j < 16; ++j) {
            const int k = wv * 16 + j;
            float h = sd + acc[j];
            float r = s_rel[k * 64 + d];
            float hr = h * r;
            float hh = h * h;
            #pragma unroll
            for (int m = 1; m < 64; m <<= 1) {
                hr += __shfl_xor(hr, m, 64);
                hh += __shfl_xor(hh, m, 64);
            }
            if (lane == 0) {
                float denom = fmaxf(sqrtf(hh), EPS) * s_rn[k];
                float c = hr / denom;
                float e = (c > 0.f) ? c : ALPHA * c;
                s_e[k] = (s_mask[k] > 0) ? e : NEG_INF;
            }
        }
        __syncthreads();

        // ---- softmax over k (wave 0 only) ----
        if (tid < 64) {
            float v = s_e[tid];
            float M = v;
            #pragma unroll
            for (int m = 1; m < 64; m <<= 1) M = fmaxf(M, __shfl_xor(M, m, 64));
            float p = __expf(v - M);
            float S = p;
            #pragma unroll
            for (int m = 1; m < 64; m <<= 1) S += __shfl_xor(S, m, 64);
            s_att[tid] = p / S;
        }
        __syncthreads();

        // ---- agg[d] = sum_k att[k] * dst[k][d]; residual ----
        float agg = 0.f;
        #pragma unroll
        for (int k4 = 0; k4 < 16; ++k4) {
            float4 av = *(const float4*)&s_att[4 * k4];  // broadcast
            agg += av.x * s_dst[(4*k4+0) * 64 + d] + av.y * s_dst[(4*k4+1) * 64 + d]
                 + av.z * s_dst[(4*k4+2) * 64 + d] + av.w * s_dst[(4*k4+3) * 64 + d];
        }
        x_d = x_d + agg;

        if (ll == 0) {
            // publish x for layer 2's s-phase (all waves computed identical x_d)
            if (tid < 64) s_x[tid] = x_d;
            __syncthreads();
        }
    }

    if (wv == 0 && n < out_rows) {
        out[(size_t)n * DD + d] = x_d;
    }
}

extern "C" void kernel_launch(void* const* d_in, const int* in_sizes, int n_in,
                              void* d_out, int out_size, void* d_ws, size_t ws_size,
                              hipStream_t stream) {
    const float* src  = (const float*)d_in[0];
    const float* dst  = (const float*)d_in[1];
    const float* rel  = (const float*)d_in[2];
    const float* fcw  = (const float*)d_in[3];
    const float* fcb  = (const float*)d_in[4];
    const int*   mask = (const int*)d_in[5];
    float* out = (float*)d_out;

    const int n_rows   = in_sizes[0] / DD;   // 50000
    const int out_rows = out_size / DD;

    kgat_fused<<<n_rows, 256, 0, stream>>>(src, dst, rel, fcw, fcb, mask, out, out_rows);
}